// Round 1
// baseline (444.390 us; speedup 1.0000x reference)
//
#include <hip/hip_runtime.h>
#include <hip/hip_bf16.h>

#define NLAT_IN  480
#define NLON_IN  960
#define NLAT_OUT 721
#define NLON_OUT 1440
#define KSIZE    9
#define NNZ      20
#define CH       32   // C_IN == C_OUT == 32

typedef __bf16 bf16x8 __attribute__((ext_vector_type(8)));
typedef float  f32x4  __attribute__((ext_vector_type(4)));

__device__ __forceinline__ unsigned short f2bf(float f) {
    unsigned u = __float_as_uint(f);
    u += 0x7fffu + ((u >> 16) & 1u);   // round-to-nearest-even
    return (unsigned short)(u >> 16);
}

// ---------------------------------------------------------------------------
// Kernel 1: bilinear resample (480,960) -> (721,1440), output channel-last
// x_r[h][w][c] as bf16.  One thread per (h,w), 32 channels each.
// ---------------------------------------------------------------------------
__global__ void resample_kernel(const float* __restrict__ x,
                                unsigned short* __restrict__ xr) {
    int idx = blockIdx.x * blockDim.x + threadIdx.x;
    if (idx >= NLAT_OUT * NLON_OUT) return;
    int h = idx / NLON_OUT;
    int w = idx - h * NLON_OUT;

    float pos_h = (float)h * (479.0f / 720.0f);
    int h0 = (int)floorf(pos_h);
    if (h0 < 0) h0 = 0;
    if (h0 > NLAT_IN - 2) h0 = NLAT_IN - 2;
    float fh = pos_h - (float)h0;

    float pos_w = (float)w * ((float)NLON_IN / (float)NLON_OUT);
    int w0 = (int)floorf(pos_w);
    float fw = pos_w - (float)w0;
    w0 %= NLON_IN;
    int w1 = w0 + 1; if (w1 >= NLON_IN) w1 -= NLON_IN;

    float c00 = (1.f - fh) * (1.f - fw);
    float c10 = fh * (1.f - fw);
    float c01 = (1.f - fh) * fw;
    float c11 = fh * fw;

    size_t o00 = (size_t)h0 * NLON_IN + w0;
    size_t o10 = o00 + NLON_IN;
    size_t o01 = (size_t)h0 * NLON_IN + w1;
    size_t o11 = o01 + NLON_IN;

    unsigned* op = (unsigned*)(xr + (size_t)idx * CH);
    const size_t plane = (size_t)NLAT_IN * NLON_IN;
#pragma unroll
    for (int c = 0; c < CH; c += 2) {
        const float* p0 = x + (size_t)c * plane;
        const float* p1 = p0 + plane;
        float v0 = p0[o00] * c00 + p0[o10] * c10 + p0[o01] * c01 + p0[o11] * c11;
        float v1 = p1[o00] * c00 + p1[o10] * c10 + p1[o01] * c01 + p1[o11] * c11;
        op[c >> 1] = (unsigned)f2bf(v0) | ((unsigned)f2bf(v1) << 16);
    }
}

// ---------------------------------------------------------------------------
// Kernel 2: weff[h][nz][oc][c] = sum_k weight[oc][c][k] * psi_vals[k][h][nz]
// bf16 output.  One thread computes 2 consecutive c (one packed dword).
// ---------------------------------------------------------------------------
__global__ void weff_kernel(const float* __restrict__ weight,
                            const float* __restrict__ psi_vals,
                            unsigned short* __restrict__ weff) {
    int idx = blockIdx.x * blockDim.x + threadIdx.x;  // over 721*20*512
    if (idx >= NLAT_OUT * NNZ * (CH * CH / 2)) return;
    int cpair = idx & 511;          // oc*16 + c/2
    int hnz   = idx >> 9;           // h*20 + nz
    int oc = cpair >> 4;
    int c  = (cpair & 15) * 2;

    const float* wp0 = weight + ((size_t)oc * CH + c) * KSIZE;
    const float* wp1 = wp0 + KSIZE;
    const float* pv  = psi_vals + hnz;      // psi_vals[k][h][nz], k stride = 721*20
    float a0 = 0.f, a1 = 0.f;
#pragma unroll
    for (int k = 0; k < KSIZE; ++k) {
        float p = pv[(size_t)k * (NLAT_OUT * NNZ)];
        a0 += wp0[k] * p;
        a1 += wp1[k] * p;
    }
    ((unsigned*)weff)[idx] = (unsigned)f2bf(a0) | ((unsigned)f2bf(a1) << 16);
}

// ---------------------------------------------------------------------------
// Kernel 3: disco conv via MFMA.
// Grid (5, 721); block = 384 threads (6 waves). Wave wv owns 48 w-columns:
// w = wblk*288 + wv*48 + s*16 + (lane&15), s=0..2.  M=32 split in 2 halves.
// Per nz: 1 MFMA K=32 step covers all input channels.
// Fragment maps (guide §3, HW-verified):
//   A[m=lane&15][k=quad*8+j]   B[k=quad*8+j][n=lane&15]
//   D[row=quad*4+r][col=lane&15]
// ---------------------------------------------------------------------------
__global__ __launch_bounds__(384) void disco_kernel(
        const unsigned short* __restrict__ xr,     // [721][1440][32] bf16
        const unsigned short* __restrict__ weff,   // [721][20][32][32] bf16
        const int* __restrict__ psi_hi,            // [721][20]
        const int* __restrict__ psi_dw,            // [721][20]
        float* __restrict__ out) {                 // [32][721][1440]
    int h    = blockIdx.y;
    int wblk = blockIdx.x;
    int wave = threadIdx.x >> 6;
    int lane = threadIdx.x & 63;
    int l15  = lane & 15;
    int quad = lane >> 4;
    int c0   = quad * 8;
    int wbase = wblk * 288 + wave * 48;

    f32x4 acc[2][3] = {};

    const unsigned short* weff_h = weff + (size_t)h * (NNZ * CH * CH);
    const int* hip_ = psi_hi + h * NNZ;
    const int* dwp  = psi_dw + h * NNZ;

#pragma unroll 2
    for (int nz = 0; nz < NNZ; ++nz) {
        int hi = hip_[nz];
        int dw = dwp[nz];
        const unsigned short* wf = weff_h + nz * (CH * CH);
        bf16x8 a0 = *(const bf16x8*)(wf + l15 * CH + c0);
        bf16x8 a1 = *(const bf16x8*)(wf + (16 + l15) * CH + c0);
        const unsigned short* xrow = xr + (size_t)hi * (NLON_OUT * CH);
#pragma unroll
        for (int s = 0; s < 3; ++s) {
            int w = wbase + s * 16 + l15 + dw;
            if (w >= NLON_OUT) w -= NLON_OUT;
            bf16x8 b = *(const bf16x8*)(xrow + w * CH + c0);
            acc[0][s] = __builtin_amdgcn_mfma_f32_16x16x32_bf16(a0, b, acc[0][s], 0, 0, 0);
            acc[1][s] = __builtin_amdgcn_mfma_f32_16x16x32_bf16(a1, b, acc[1][s], 0, 0, 0);
        }
    }

#pragma unroll
    for (int hh = 0; hh < 2; ++hh)
#pragma unroll
        for (int s = 0; s < 3; ++s)
#pragma unroll
            for (int r = 0; r < 4; ++r) {
                int oc = hh * 16 + quad * 4 + r;
                int w  = wbase + s * 16 + l15;
                out[((size_t)oc * NLAT_OUT + h) * NLON_OUT + w] = acc[hh][s][r];
            }
}

// ---------------------------------------------------------------------------
extern "C" void kernel_launch(void* const* d_in, const int* in_sizes, int n_in,
                              void* d_out, int out_size, void* d_ws, size_t ws_size,
                              hipStream_t stream) {
    const float* x        = (const float*)d_in[0];
    const float* weight   = (const float*)d_in[1];
    const float* psi_vals = (const float*)d_in[2];
    const int*   psi_hi   = (const int*)d_in[3];
    const int*   psi_dw   = (const int*)d_in[4];
    float* out = (float*)d_out;

    // workspace layout: x_r bf16 [721][1440][32] = 66,447,360 B, then
    // weff bf16 [721][20][32][32] = 29,532,160 B  (total ~96 MB)
    unsigned short* xr = (unsigned short*)d_ws;
    unsigned short* wf = (unsigned short*)((char*)d_ws + (size_t)NLAT_OUT * NLON_OUT * CH * 2);

    {
        int n = NLAT_OUT * NLON_OUT;
        resample_kernel<<<(n + 255) / 256, 256, 0, stream>>>(x, xr);
    }
    {
        int n = NLAT_OUT * NNZ * (CH * CH / 2);
        weff_kernel<<<(n + 255) / 256, 256, 0, stream>>>(weight, psi_vals, wf);
    }
    {
        dim3 grid(NLON_OUT / 288, NLAT_OUT);
        disco_kernel<<<grid, 384, 0, stream>>>(xr, wf, psi_hi, psi_dw, out);
    }
}

// Round 2
// 378.398 us; speedup vs baseline: 1.1744x; 1.1744x over previous
//
#include <hip/hip_runtime.h>
#include <hip/hip_bf16.h>

#define NLAT_IN  480
#define NLON_IN  960
#define NLAT_OUT 721
#define NLON_OUT 1440
#define KSIZE    9
#define NNZ      20
#define CH       32   // C_IN == C_OUT == 32

typedef __bf16 bf16x8 __attribute__((ext_vector_type(8)));
typedef float  f32x4  __attribute__((ext_vector_type(4)));

__device__ __forceinline__ unsigned short f2bf(float f) {
    unsigned u = __float_as_uint(f);
    u += 0x7fffu + ((u >> 16) & 1u);   // round-to-nearest-even
    return (unsigned short)(u >> 16);
}

// ---------------------------------------------------------------------------
// Kernel 1: bilinear resample (480,960) -> (721,1440), channel-last bf16 out.
// Block = 256 threads handles one output row h and 180 output columns.
// Input tile (2 rows x 32 ch x 124 cols) staged in LDS via float4 loads.
// base_in = bx*120 is exact (180 * 2/3), and 960 % 4 == 0 so the periodic
// wrap (last block only) never splits a float4.
// ---------------------------------------------------------------------------
#define W_TILE   180
#define IN_LD4   31            // 31 float4 = 124 input cols staged
#define LDS_PITCH 129          // c-stride ≡ 1 (mod 32): good bank spread

__global__ __launch_bounds__(256) void resample_kernel(
        const float* __restrict__ x,
        unsigned short* __restrict__ xr) {
    __shared__ float ld[2 * CH * LDS_PITCH];

    int h  = blockIdx.y;
    int bx = blockIdx.x;
    int wb = bx * W_TILE;
    int base_in = bx * (W_TILE * 2 / 3);   // = bx*120

    float pos_h = (float)h * (479.0f / 720.0f);
    int h0 = (int)floorf(pos_h);
    if (h0 < 0) h0 = 0;
    if (h0 > NLAT_IN - 2) h0 = NLAT_IN - 2;
    float fh = pos_h - (float)h0;

    // ---- stage: 2 rows x 32 ch x 31 float4 ----
    const int t = threadIdx.x;
    for (int i = 0; i < 8; ++i) {
        int lin = i * 256 + t;             // [0, 1984)
        if (lin < 2 * CH * IN_LD4) {
            int r   = lin / (CH * IN_LD4);
            int rem = lin - r * (CH * IN_LD4);
            int c   = rem / IN_LD4;
            int j   = rem - c * IN_LD4;
            int src = base_in + 4 * j;
            if (src >= NLON_IN) src -= NLON_IN;      // only last block
            f32x4 v = *(const f32x4*)(x + ((size_t)c * NLAT_IN + h0 + r) * NLON_IN + src);
            float* dst = ld + (r * CH + c) * LDS_PITCH + 4 * j;
            dst[0] = v.x; dst[1] = v.y; dst[2] = v.z; dst[3] = v.w;
        }
    }
    __syncthreads();

    // ---- compute: 180 w x 16 c-pairs = 2880 dwords, 11.25/thread ----
    float ifh = 1.0f - fh;
    for (int i = 0; i < 12; ++i) {
        int d = i * 256 + t;               // [0, 2880)
        if (d >= W_TILE * (CH / 2)) break;
        int w_l   = d >> 4;
        int cpair = d & 15;
        int c = cpair * 2;
        int w = wb + w_l;
        float pos_w = (float)w * ((float)NLON_IN / (float)NLON_OUT);
        int w0 = (int)floorf(pos_w);
        float fw = pos_w - (float)w0;
        int wl0 = w0 - base_in;            // [0, 120]
        float ifw = 1.0f - fw;

        const float* r0 = ld + c * LDS_PITCH + wl0;
        const float* r1 = r0 + CH * LDS_PITCH;
        float v0 = ifh * (ifw * r0[0] + fw * r0[1]) + fh * (ifw * r1[0] + fw * r1[1]);
        const float* q0 = r0 + LDS_PITCH;
        const float* q1 = r1 + LDS_PITCH;
        float v1 = ifh * (ifw * q0[0] + fw * q0[1]) + fh * (ifw * q1[0] + fw * q1[1]);

        ((unsigned*)xr)[((size_t)h * NLON_OUT + w) * (CH / 2) + cpair] =
            (unsigned)f2bf(v0) | ((unsigned)f2bf(v1) << 16);
    }
}

// ---------------------------------------------------------------------------
// Kernel 2: weff[h][nz][oc][c] = sum_k weight[oc][c][k] * psi_vals[k][h][nz]
// Weight (36.9 KB) staged in LDS transposed to [k][oc][c] so the inner
// float2 read address is independent of the lane's hnz -> broadcast.
// Block = 256 threads handles 16 hnz.
// ---------------------------------------------------------------------------
__global__ __launch_bounds__(256) void weff_kernel(
        const float* __restrict__ weight,
        const float* __restrict__ psi_vals,
        unsigned short* __restrict__ weff) {
    __shared__ float wl[KSIZE * CH * CH];   // [k][oc][c]

    const int t = threadIdx.x;
    // stage weight: 9216 floats = 2304 float4, coalesced read, scattered write
    for (int i = 0; i < 9; ++i) {
        int lin = i * 256 + t;              // [0, 2304)
        if (lin < KSIZE * CH * CH / 4) {
            f32x4 v = *(const f32x4*)(weight + lin * 4);
            float vv[4] = {v.x, v.y, v.z, v.w};
#pragma unroll
            for (int q = 0; q < 4; ++q) {
                int l4 = lin * 4 + q;       // = (oc*32 + c)*9 + k
                int k  = l4 % KSIZE;
                int occ = l4 / KSIZE;       // oc*32 + c
                wl[(k * CH * CH) + occ - (occ & 31) + (occ & 31)] = 0; // placeholder avoided
            }
        }
    }
    // NOTE: the loop above must write transposed; rewritten cleanly below.
    __syncthreads();
    // (real staging below — the above wrote nothing meaningful; redo)
    for (int i = 0; i < 9; ++i) {
        int lin = i * 256 + t;
        if (lin < KSIZE * CH * CH / 4) {
            f32x4 v = *(const f32x4*)(weight + lin * 4);
            float vv[4] = {v.x, v.y, v.z, v.w};
#pragma unroll
            for (int q = 0; q < 4; ++q) {
                int l4 = lin * 4 + q;       // = (oc*CH + c)*KSIZE + k
                int k  = l4 % KSIZE;
                int occ = l4 / KSIZE;       // oc*CH + c
                wl[k * (CH * CH) + occ] = vv[q];
            }
        }
    }
    __syncthreads();

    int hnz = blockIdx.x * 16 + (t >> 4);
    int cp  = t & 15;
    if (hnz >= NLAT_OUT * NNZ) return;

    float p[KSIZE];
#pragma unroll
    for (int k = 0; k < KSIZE; ++k)
        p[k] = psi_vals[(size_t)k * (NLAT_OUT * NNZ) + hnz];

    unsigned* outp = (unsigned*)weff + (size_t)hnz * (CH * CH / 2) + cp;
#pragma unroll 4
    for (int oc = 0; oc < CH; ++oc) {
        float a0 = 0.f, a1 = 0.f;
        const float* wb = wl + oc * CH + cp * 2;
#pragma unroll
        for (int k = 0; k < KSIZE; ++k) {
            a0 += wb[k * (CH * CH)]     * p[k];
            a1 += wb[k * (CH * CH) + 1] * p[k];
        }
        outp[oc * 16] = (unsigned)f2bf(a0) | ((unsigned)f2bf(a1) << 16);
    }
}

// ---------------------------------------------------------------------------
// Kernel 3: disco conv via MFMA, XCD-striped.
// 920 blocks: xcd = bid&7 owns hblk in [xcd*23, xcd*23+23); k=bid>>3 orders
// the 5 w-chunks of one hblk adjacently in time on the same XCD.
// Each block processes 4 consecutive h (rows needed: h0-2 .. h0+5 -> 8 rows,
// halo-shared with the XCD-adjacent hblk) x 288 w.
// Fragment maps (HW-verified): A[m=lane&15][k=quad*8+j],
// B[k=quad*8+j][n=lane&15], D[row=quad*4+r][col=lane&15].
// ---------------------------------------------------------------------------
#define HBLK 181   // ceil(721/4)

__global__ __launch_bounds__(384) void disco_kernel(
        const unsigned short* __restrict__ xr,     // [721][1440][32] bf16
        const unsigned short* __restrict__ weff,   // [721][20][32][32] bf16
        const int* __restrict__ psi_hi,            // [721][20]
        const int* __restrict__ psi_dw,            // [721][20]
        float* __restrict__ out) {                 // [32][721][1440]
    int bid  = blockIdx.x;
    int xcd  = bid & 7;
    int k    = bid >> 3;                 // [0,115)
    int hblk = xcd * 23 + k / 5;
    int wblk = k % 5;
    if (hblk >= HBLK) return;

    int wave = threadIdx.x >> 6;
    int lane = threadIdx.x & 63;
    int l15  = lane & 15;
    int quad = lane >> 4;
    int c0   = quad * 8;
    int wbase = wblk * 288 + wave * 48;

    for (int j = 0; j < 4; ++j) {
        int h = hblk * 4 + j;
        if (h >= NLAT_OUT) break;

        f32x4 acc[2][3] = {};
        const unsigned short* weff_h = weff + (size_t)h * (NNZ * CH * CH);
        const int* hip_ = psi_hi + h * NNZ;
        const int* dwp  = psi_dw + h * NNZ;

#pragma unroll 2
        for (int nz = 0; nz < NNZ; ++nz) {
            int hi = hip_[nz];
            int dw = dwp[nz];
            const unsigned short* wf = weff_h + nz * (CH * CH);
            bf16x8 a0 = *(const bf16x8*)(wf + l15 * CH + c0);
            bf16x8 a1 = *(const bf16x8*)(wf + (16 + l15) * CH + c0);
            const unsigned short* xrow = xr + (size_t)hi * (NLON_OUT * CH);
#pragma unroll
            for (int s = 0; s < 3; ++s) {
                int w = wbase + s * 16 + l15 + dw;
                if (w >= NLON_OUT) w -= NLON_OUT;
                bf16x8 b = *(const bf16x8*)(xrow + w * CH + c0);
                acc[0][s] = __builtin_amdgcn_mfma_f32_16x16x32_bf16(a0, b, acc[0][s], 0, 0, 0);
                acc[1][s] = __builtin_amdgcn_mfma_f32_16x16x32_bf16(a1, b, acc[1][s], 0, 0, 0);
            }
        }

#pragma unroll
        for (int hh = 0; hh < 2; ++hh)
#pragma unroll
            for (int s = 0; s < 3; ++s)
#pragma unroll
                for (int r = 0; r < 4; ++r) {
                    int oc = hh * 16 + quad * 4 + r;
                    int w  = wbase + s * 16 + l15;
                    out[((size_t)oc * NLAT_OUT + h) * NLON_OUT + w] = acc[hh][s][r];
                }
    }
}

// ---------------------------------------------------------------------------
extern "C" void kernel_launch(void* const* d_in, const int* in_sizes, int n_in,
                              void* d_out, int out_size, void* d_ws, size_t ws_size,
                              hipStream_t stream) {
    const float* x        = (const float*)d_in[0];
    const float* weight   = (const float*)d_in[1];
    const float* psi_vals = (const float*)d_in[2];
    const int*   psi_hi   = (const int*)d_in[3];
    const int*   psi_dw   = (const int*)d_in[4];
    float* out = (float*)d_out;

    // workspace: xr bf16 [721][1440][32] = 66,447,360 B, then
    // weff bf16 [721][20][32][32] = 29,532,160 B
    unsigned short* xr = (unsigned short*)d_ws;
    unsigned short* wf = (unsigned short*)((char*)d_ws + (size_t)NLAT_OUT * NLON_OUT * CH * 2);

    {
        dim3 grid(NLON_OUT / W_TILE, NLAT_OUT);   // 8 x 721
        resample_kernel<<<grid, 256, 0, stream>>>(x, xr);
    }
    {
        int nblk = (NLAT_OUT * NNZ + 15) / 16;    // 902
        weff_kernel<<<nblk, 256, 0, stream>>>(weight, psi_vals, wf);
    }
    {
        disco_kernel<<<920, 384, 0, stream>>>(xr, wf, psi_hi, psi_dw, out);
    }
}

// Round 3
// 341.994 us; speedup vs baseline: 1.2994x; 1.1064x over previous
//
#include <hip/hip_runtime.h>
#include <hip/hip_bf16.h>

#define NLAT_IN  480
#define NLON_IN  960
#define NLAT_OUT 721
#define NLON_OUT 1440
#define KSIZE    9
#define NNZ      20
#define CH       32   // C_IN == C_OUT == 32

typedef __bf16 bf16x8 __attribute__((ext_vector_type(8)));
typedef float  f32x4  __attribute__((ext_vector_type(4)));

__device__ __forceinline__ unsigned short f2bf(float f) {
    unsigned u = __float_as_uint(f);
    u += 0x7fffu + ((u >> 16) & 1u);   // round-to-nearest-even
    return (unsigned short)(u >> 16);
}

// ---------------------------------------------------------------------------
// Kernel 1: bilinear resample (480,960) -> (721,1440), channel-last bf16 out.
// ---------------------------------------------------------------------------
#define W_TILE   180
#define IN_LD4   31            // 31 float4 = 124 input cols staged
#define LDS_PITCH 129

__global__ __launch_bounds__(256) void resample_kernel(
        const float* __restrict__ x,
        unsigned short* __restrict__ xr) {
    __shared__ float ld[2 * CH * LDS_PITCH];

    int h  = blockIdx.y;
    int bx = blockIdx.x;
    int wb = bx * W_TILE;
    int base_in = bx * (W_TILE * 2 / 3);   // = bx*120

    float pos_h = (float)h * (479.0f / 720.0f);
    int h0 = (int)floorf(pos_h);
    if (h0 < 0) h0 = 0;
    if (h0 > NLAT_IN - 2) h0 = NLAT_IN - 2;
    float fh = pos_h - (float)h0;

    const int t = threadIdx.x;
    for (int i = 0; i < 8; ++i) {
        int lin = i * 256 + t;             // [0, 1984)
        if (lin < 2 * CH * IN_LD4) {
            int r   = lin / (CH * IN_LD4);
            int rem = lin - r * (CH * IN_LD4);
            int c   = rem / IN_LD4;
            int j   = rem - c * IN_LD4;
            int src = base_in + 4 * j;
            if (src >= NLON_IN) src -= NLON_IN;      // only last block
            f32x4 v = *(const f32x4*)(x + ((size_t)c * NLAT_IN + h0 + r) * NLON_IN + src);
            float* dst = ld + (r * CH + c) * LDS_PITCH + 4 * j;
            dst[0] = v.x; dst[1] = v.y; dst[2] = v.z; dst[3] = v.w;
        }
    }
    __syncthreads();

    float ifh = 1.0f - fh;
    for (int i = 0; i < 12; ++i) {
        int d = i * 256 + t;               // [0, 2880)
        if (d >= W_TILE * (CH / 2)) break;
        int w_l   = d >> 4;
        int cpair = d & 15;
        int c = cpair * 2;
        int w = wb + w_l;
        float pos_w = (float)w * ((float)NLON_IN / (float)NLON_OUT);
        int w0 = (int)floorf(pos_w);
        float fw = pos_w - (float)w0;
        int wl0 = w0 - base_in;            // [0, 120]
        float ifw = 1.0f - fw;

        const float* r0 = ld + c * LDS_PITCH + wl0;
        const float* r1 = r0 + CH * LDS_PITCH;
        float v0 = ifh * (ifw * r0[0] + fw * r0[1]) + fh * (ifw * r1[0] + fw * r1[1]);
        const float* q0 = r0 + LDS_PITCH;
        const float* q1 = r1 + LDS_PITCH;
        float v1 = ifh * (ifw * q0[0] + fw * q0[1]) + fh * (ifw * q1[0] + fw * q1[1]);

        ((unsigned*)xr)[((size_t)h * NLON_OUT + w) * (CH / 2) + cpair] =
            (unsigned)f2bf(v0) | ((unsigned)f2bf(v1) << 16);
    }
}

// ---------------------------------------------------------------------------
// Kernel 2: weff[h][nz][oc][c] = sum_k weight[oc][c][k] * psi_vals[k][h][nz]
// Weight staged in LDS transposed to [k][oc][c]; block = 16 hnz.
// ---------------------------------------------------------------------------
__global__ __launch_bounds__(256) void weff_kernel(
        const float* __restrict__ weight,
        const float* __restrict__ psi_vals,
        unsigned short* __restrict__ weff) {
    __shared__ float wl[KSIZE * CH * CH];   // [k][oc][c]

    const int t = threadIdx.x;
    for (int i = 0; i < 9; ++i) {
        int lin = i * 256 + t;              // [0, 2304)
        if (lin < KSIZE * CH * CH / 4) {
            f32x4 v = *(const f32x4*)(weight + lin * 4);
            float vv[4] = {v.x, v.y, v.z, v.w};
#pragma unroll
            for (int q = 0; q < 4; ++q) {
                int l4 = lin * 4 + q;       // = (oc*CH + c)*KSIZE + k
                int k  = l4 % KSIZE;
                int occ = l4 / KSIZE;       // oc*CH + c
                wl[k * (CH * CH) + occ] = vv[q];
            }
        }
    }
    __syncthreads();

    int hnz = blockIdx.x * 16 + (t >> 4);
    int cp  = t & 15;
    if (hnz >= NLAT_OUT * NNZ) return;

    float p[KSIZE];
#pragma unroll
    for (int k = 0; k < KSIZE; ++k)
        p[k] = psi_vals[(size_t)k * (NLAT_OUT * NNZ) + hnz];

    unsigned* outp = (unsigned*)weff + (size_t)hnz * (CH * CH / 2) + cp;
#pragma unroll 4
    for (int oc = 0; oc < CH; ++oc) {
        float a0 = 0.f, a1 = 0.f;
        const float* wb = wl + oc * CH + cp * 2;
#pragma unroll
        for (int k = 0; k < KSIZE; ++k) {
            a0 += wb[k * (CH * CH)]     * p[k];
            a1 += wb[k * (CH * CH) + 1] * p[k];
        }
        outp[oc * 16] = (unsigned)f2bf(a0) | ((unsigned)f2bf(a1) << 16);
    }
}

// ---------------------------------------------------------------------------
// Kernel 3: disco conv via MFMA with full LDS staging of the gather tile.
// Block = 384 thr (6 waves) owns 4 h-rows x 288 w-cols.
// Staged tile: rows [h0-2, h0+5] x cols [wbase-16, wbase+304) x 32ch bf16
//   = 8*320*32*2 = 163840 B = all 160 KiB of LDS.  All 4 h x 20 nz x 3 s
// B-fragments then come from LDS (conflict-free contiguous ds_read_b128).
// 16-col chunks are always contiguous in global memory (16 | 1440, and block
// starts are multiples of 16), so global_load_lds dwordx4 stages 1 KiB/inst.
// XCD-striped: bid&7 = XCD, consecutive work per XCD shares rows in L2.
// Fragment maps (HW-verified): A[m=lane&15][k=quad*8+j],
// B[k=quad*8+j][n=lane&15], D[row=quad*4+r][col=lane&15].
// ---------------------------------------------------------------------------
#define ST_ROWS 8
#define ST_COLS 320
#define NPAIR   905            // 181 hblk * 5 wblk
#define PER_XCD 114            // ceil(905/8)

__global__ __launch_bounds__(384) void disco_kernel(
        const unsigned short* __restrict__ xr,     // [721][1440][32] bf16
        const unsigned short* __restrict__ weff,   // [721][20][32][32] bf16
        const int* __restrict__ psi_hi,            // [721][20]
        const int* __restrict__ psi_dw,            // [721][20]
        float* __restrict__ out) {                 // [32][721][1440]
    __shared__ unsigned short st[ST_ROWS * ST_COLS * CH];   // 160 KiB

    int bid = blockIdx.x;
    int xcd = bid & 7;
    int p   = xcd * PER_XCD + (bid >> 3);
    if (p >= NPAIR) return;
    int hblk = p / 5;
    int wblk = p - hblk * 5;
    int h0    = hblk * 4;
    int wbase_blk = wblk * 288;

    int wave = threadIdx.x >> 6;
    int lane = threadIdx.x & 63;
    int l15  = lane & 15;
    int quad = lane >> 4;
    int c0   = quad * 8;

    // ---- stage 8 rows x 320 cols: 160 chunks of 16 cols (1 KiB each) ----
    int cstart = wbase_blk - 16;
    if (cstart < 0) cstart += NLON_OUT;     // multiple of 16, <= 1424
    for (int i = wave; i < ST_ROWS * (ST_COLS / 16); i += 6) {
        int r  = i / (ST_COLS / 16);
        int ck = i - r * (ST_COLS / 16);
        int gh = h0 - 2 + r;
        gh = gh < 0 ? 0 : (gh > NLAT_OUT - 1 ? NLAT_OUT - 1 : gh);
        int gc = cstart + ck * 16;
        if (gc >= NLON_OUT) gc -= NLON_OUT;  // chunk never crosses the wrap
        const unsigned short* gp = xr + ((size_t)gh * NLON_OUT + gc) * CH + lane * 8;
        unsigned short* lp = st + (r * ST_COLS + ck * 16) * CH;
        __builtin_amdgcn_global_load_lds(
            (const __attribute__((address_space(1))) void*)gp,
            (__attribute__((address_space(3))) void*)lp, 16, 0, 0);
    }
    __syncthreads();

    // ---- compute: 4 h-rows, all B-fragments from LDS ----
    int wcol0 = 16 + wave * 48;            // LDS col of this wave's w=+0, s=0
    for (int j = 0; j < 4; ++j) {
        int h = h0 + j;
        if (h >= NLAT_OUT) break;

        f32x4 acc[2][3] = {};
        const unsigned short* weff_h = weff + (size_t)h * (NNZ * CH * CH);
        const int* hip_ = psi_hi + h * NNZ;
        const int* dwp  = psi_dw + h * NNZ;

#pragma unroll 2
        for (int nz = 0; nz < NNZ; ++nz) {
            int hi = hip_[nz];
            int dw = dwp[nz];
            int shift = dw > 720 ? dw - NLON_OUT : dw;   // data range: [-10,10]
            int rloc  = hi - h0 + 2;                     // [0, 7]
            const unsigned short* wf = weff_h + nz * (CH * CH);
            bf16x8 a0 = *(const bf16x8*)(wf + l15 * CH + c0);
            bf16x8 a1 = *(const bf16x8*)(wf + (16 + l15) * CH + c0);
            const unsigned short* srow = st + (size_t)rloc * (ST_COLS * CH);
            int cbase = wcol0 + l15 + shift;             // [6, 313]
#pragma unroll
            for (int s = 0; s < 3; ++s) {
                bf16x8 b = *(const bf16x8*)(srow + (cbase + s * 16) * CH + c0);
                acc[0][s] = __builtin_amdgcn_mfma_f32_16x16x32_bf16(a0, b, acc[0][s], 0, 0, 0);
                acc[1][s] = __builtin_amdgcn_mfma_f32_16x16x32_bf16(a1, b, acc[1][s], 0, 0, 0);
            }
        }

#pragma unroll
        for (int hh = 0; hh < 2; ++hh)
#pragma unroll
            for (int s = 0; s < 3; ++s)
#pragma unroll
                for (int r = 0; r < 4; ++r) {
                    int oc = hh * 16 + quad * 4 + r;
                    int w  = wbase_blk + wave * 48 + s * 16 + l15;
                    out[((size_t)oc * NLAT_OUT + h) * NLON_OUT + w] = acc[hh][s][r];
                }
    }
}

// ---------------------------------------------------------------------------
extern "C" void kernel_launch(void* const* d_in, const int* in_sizes, int n_in,
                              void* d_out, int out_size, void* d_ws, size_t ws_size,
                              hipStream_t stream) {
    const float* x        = (const float*)d_in[0];
    const float* weight   = (const float*)d_in[1];
    const float* psi_vals = (const float*)d_in[2];
    const int*   psi_hi   = (const int*)d_in[3];
    const int*   psi_dw   = (const int*)d_in[4];
    float* out = (float*)d_out;

    // workspace: xr bf16 [721][1440][32] = 66,447,360 B, then
    // weff bf16 [721][20][32][32] = 29,532,160 B
    unsigned short* xr = (unsigned short*)d_ws;
    unsigned short* wf = (unsigned short*)((char*)d_ws + (size_t)NLAT_OUT * NLON_OUT * CH * 2);

    {
        dim3 grid(NLON_OUT / W_TILE, NLAT_OUT);   // 8 x 721
        resample_kernel<<<grid, 256, 0, stream>>>(x, xr);
    }
    {
        int nblk = (NLAT_OUT * NNZ + 15) / 16;    // 902
        weff_kernel<<<nblk, 256, 0, stream>>>(weight, psi_vals, wf);
    }
    {
        disco_kernel<<<8 * PER_XCD, 384, 0, stream>>>(xr, wf, psi_hi, psi_dw, out);
    }
}

// Round 4
// 316.400 us; speedup vs baseline: 1.4045x; 1.0809x over previous
//
#include <hip/hip_runtime.h>
#include <hip/hip_bf16.h>

#define NLAT_IN  480
#define NLON_IN  960
#define NLAT_OUT 721
#define NLON_OUT 1440
#define KSIZE    9
#define NNZ      20
#define CH       32   // C_IN == C_OUT == 32

typedef __bf16 bf16x8 __attribute__((ext_vector_type(8)));
typedef float  f32x4  __attribute__((ext_vector_type(4)));

__device__ __forceinline__ unsigned short f2bf(float f) {
    unsigned u = __float_as_uint(f);
    u += 0x7fffu + ((u >> 16) & 1u);   // round-to-nearest-even
    return (unsigned short)(u >> 16);
}

// ---------------------------------------------------------------------------
// Kernel 1: bilinear resample (480,960) -> (721,1440), channel-last bf16 out.
// ---------------------------------------------------------------------------
#define W_TILE   180
#define IN_LD4   31            // 31 float4 = 124 input cols staged
#define LDS_PITCH 129

__global__ __launch_bounds__(256) void resample_kernel(
        const float* __restrict__ x,
        unsigned short* __restrict__ xr) {
    __shared__ float ld[2 * CH * LDS_PITCH];

    int h  = blockIdx.y;
    int bx = blockIdx.x;
    int wb = bx * W_TILE;
    int base_in = bx * (W_TILE * 2 / 3);   // = bx*120

    float pos_h = (float)h * (479.0f / 720.0f);
    int h0 = (int)floorf(pos_h);
    if (h0 < 0) h0 = 0;
    if (h0 > NLAT_IN - 2) h0 = NLAT_IN - 2;
    float fh = pos_h - (float)h0;

    const int t = threadIdx.x;
    for (int i = 0; i < 8; ++i) {
        int lin = i * 256 + t;             // [0, 1984)
        if (lin < 2 * CH * IN_LD4) {
            int r   = lin / (CH * IN_LD4);
            int rem = lin - r * (CH * IN_LD4);
            int c   = rem / IN_LD4;
            int j   = rem - c * IN_LD4;
            int src = base_in + 4 * j;
            if (src >= NLON_IN) src -= NLON_IN;      // only last block
            f32x4 v = *(const f32x4*)(x + ((size_t)c * NLAT_IN + h0 + r) * NLON_IN + src);
            float* dst = ld + (r * CH + c) * LDS_PITCH + 4 * j;
            dst[0] = v.x; dst[1] = v.y; dst[2] = v.z; dst[3] = v.w;
        }
    }
    __syncthreads();

    float ifh = 1.0f - fh;
    for (int i = 0; i < 12; ++i) {
        int d = i * 256 + t;               // [0, 2880)
        if (d >= W_TILE * (CH / 2)) break;
        int w_l   = d >> 4;
        int cpair = d & 15;
        int c = cpair * 2;
        int w = wb + w_l;
        float pos_w = (float)w * ((float)NLON_IN / (float)NLON_OUT);
        int w0 = (int)floorf(pos_w);
        float fw = pos_w - (float)w0;
        int wl0 = w0 - base_in;            // [0, 120]
        float ifw = 1.0f - fw;

        const float* r0 = ld + c * LDS_PITCH + wl0;
        const float* r1 = r0 + CH * LDS_PITCH;
        float v0 = ifh * (ifw * r0[0] + fw * r0[1]) + fh * (ifw * r1[0] + fw * r1[1]);
        const float* q0 = r0 + LDS_PITCH;
        const float* q1 = r1 + LDS_PITCH;
        float v1 = ifh * (ifw * q0[0] + fw * q0[1]) + fh * (ifw * q1[0] + fw * q1[1]);

        ((unsigned*)xr)[((size_t)h * NLON_OUT + w) * (CH / 2) + cpair] =
            (unsigned)f2bf(v0) | ((unsigned)f2bf(v1) << 16);
    }
}

// ---------------------------------------------------------------------------
// Kernel 2: weff[h][nz][oc][c] = sum_k weight[oc][c][k] * psi_vals[k][h][nz]
// Weight staged in LDS transposed to [k][oc][c]; block = 16 hnz.
// ---------------------------------------------------------------------------
__global__ __launch_bounds__(256) void weff_kernel(
        const float* __restrict__ weight,
        const float* __restrict__ psi_vals,
        unsigned short* __restrict__ weff) {
    __shared__ float wl[KSIZE * CH * CH];   // [k][oc][c]

    const int t = threadIdx.x;
    for (int i = 0; i < 9; ++i) {
        int lin = i * 256 + t;              // [0, 2304)
        if (lin < KSIZE * CH * CH / 4) {
            f32x4 v = *(const f32x4*)(weight + lin * 4);
            float vv[4] = {v.x, v.y, v.z, v.w};
#pragma unroll
            for (int q = 0; q < 4; ++q) {
                int l4 = lin * 4 + q;       // = (oc*CH + c)*KSIZE + k
                int k  = l4 % KSIZE;
                int occ = l4 / KSIZE;       // oc*CH + c
                wl[k * (CH * CH) + occ] = vv[q];
            }
        }
    }
    __syncthreads();

    int hnz = blockIdx.x * 16 + (t >> 4);
    int cp  = t & 15;
    if (hnz >= NLAT_OUT * NNZ) return;

    float p[KSIZE];
#pragma unroll
    for (int k = 0; k < KSIZE; ++k)
        p[k] = psi_vals[(size_t)k * (NLAT_OUT * NNZ) + hnz];

    unsigned* outp = (unsigned*)weff + (size_t)hnz * (CH * CH / 2) + cp;
#pragma unroll 4
    for (int oc = 0; oc < CH; ++oc) {
        float a0 = 0.f, a1 = 0.f;
        const float* wb = wl + oc * CH + cp * 2;
#pragma unroll
        for (int k = 0; k < KSIZE; ++k) {
            a0 += wb[k * (CH * CH)]     * p[k];
            a1 += wb[k * (CH * CH) + 1] * p[k];
        }
        outp[oc * 16] = (unsigned)f2bf(a0) | ((unsigned)f2bf(a1) << 16);
    }
}

// ---------------------------------------------------------------------------
// Kernel 3: disco conv via MFMA, small-tile LDS staging for 3 blocks/CU.
// Block = 256 thr (4 waves) owns 2 h-rows x 96 w-cols.
//   wave = (jh<<1)|wq : jh = h-row within block, wq = 48-col half.
//   Each wave: 1 h x 48 w x all 32 oc (both MFMA M-halves) -> B read once.
// Staged tile: rows [h0-2, h0+3] x cols [wbase-16, wbase+112) x 32ch bf16
//   = 6*128*64 B = 48 KiB  -> 3 blocks/CU = 12 waves/CU (vs 6 in R3).
// Cross-block overlap on the CU hides staging + A-load (weff) latency.
// Fragment maps (HW-verified): A[m=lane&15][k=quad*8+j],
// B[k=quad*8+j][n=lane&15], D[row=quad*4+r][col=lane&15].
// ---------------------------------------------------------------------------
#define ST_ROWS 6
#define ST_COLS 128
#define HBLK2   361                 // ceil(721/2)
#define NPAIR   (HBLK2 * 15)        // 5415
#define PER_XCD ((NPAIR + 7) / 8)   // 677

__global__ __launch_bounds__(256, 3) void disco_kernel(
        const unsigned short* __restrict__ xr,     // [721][1440][32] bf16
        const unsigned short* __restrict__ weff,   // [721][20][32][32] bf16
        const int* __restrict__ psi_hi,            // [721][20]
        const int* __restrict__ psi_dw,            // [721][20]
        float* __restrict__ out) {                 // [32][721][1440]
    __shared__ unsigned short st[ST_ROWS * ST_COLS * CH];   // 48 KiB

    int bid = blockIdx.x;
    int xcd = bid & 7;
    int p   = xcd * PER_XCD + (bid >> 3);
    if (p >= NPAIR) return;
    int hblk = p / 15;
    int wblk = p - hblk * 15;
    int h0        = hblk * 2;
    int wbase_blk = wblk * 96;

    int wave = threadIdx.x >> 6;
    int lane = threadIdx.x & 63;
    int l15  = lane & 15;
    int quad = lane >> 4;
    int c0   = quad * 8;
    int jh   = wave >> 1;          // h-row within block
    int wq   = wave & 1;           // 48-col half

    // ---- stage 6 rows x 128 cols: 48 chunks of 16 cols (1 KiB each) ----
    int cstart = wbase_blk - 16;
    if (cstart < 0) cstart += NLON_OUT;     // multiple of 16
    for (int i = wave; i < ST_ROWS * (ST_COLS / 16); i += 4) {
        int r  = i >> 3;
        int ck = i & 7;
        int gh = h0 - 2 + r;
        gh = gh < 0 ? 0 : (gh > NLAT_OUT - 1 ? NLAT_OUT - 1 : gh);
        int gc = cstart + ck * 16;
        if (gc >= NLON_OUT) gc -= NLON_OUT;  // chunk never crosses the wrap
        const unsigned short* gp = xr + ((size_t)gh * NLON_OUT + gc) * CH + lane * 8;
        unsigned short* lp = st + (r * ST_COLS + ck * 16) * CH;
        __builtin_amdgcn_global_load_lds(
            (const __attribute__((address_space(1))) void*)gp,
            (__attribute__((address_space(3))) void*)lp, 16, 0, 0);
    }
    __syncthreads();

    // ---- compute: this wave's single h-row, B-fragments from LDS ----
    int h = h0 + jh;
    if (h < NLAT_OUT) {
        f32x4 acc[2][3] = {};
        const unsigned short* weff_h = weff + (size_t)h * (NNZ * CH * CH);
        const int* hip_ = psi_hi + h * NNZ;
        const int* dwp  = psi_dw + h * NNZ;
        int wcol0 = 16 + wq * 48 + l15;      // LDS col of this lane, s=0

#pragma unroll 2
        for (int nz = 0; nz < NNZ; ++nz) {
            int hi = hip_[nz];
            int dw = dwp[nz];
            int shift = dw > 720 ? dw - NLON_OUT : dw;   // data range: [-10,10]
            int rloc  = hi - h0 + 2;                     // [0, 5]
            const unsigned short* wf = weff_h + nz * (CH * CH);
            bf16x8 a0 = *(const bf16x8*)(wf + l15 * CH + c0);
            bf16x8 a1 = *(const bf16x8*)(wf + (16 + l15) * CH + c0);
            const unsigned short* srow = st + (size_t)rloc * (ST_COLS * CH);
            int cbase = wcol0 + shift;                   // [6, 121-32]
#pragma unroll
            for (int s = 0; s < 3; ++s) {
                bf16x8 b = *(const bf16x8*)(srow + (cbase + s * 16) * CH + c0);
                acc[0][s] = __builtin_amdgcn_mfma_f32_16x16x32_bf16(a0, b, acc[0][s], 0, 0, 0);
                acc[1][s] = __builtin_amdgcn_mfma_f32_16x16x32_bf16(a1, b, acc[1][s], 0, 0, 0);
            }
        }

#pragma unroll
        for (int hh = 0; hh < 2; ++hh)
#pragma unroll
            for (int s = 0; s < 3; ++s)
#pragma unroll
                for (int r = 0; r < 4; ++r) {
                    int oc = hh * 16 + quad * 4 + r;
                    int w  = wbase_blk + wq * 48 + s * 16 + l15;
                    out[((size_t)oc * NLAT_OUT + h) * NLON_OUT + w] = acc[hh][s][r];
                }
    }
}

// ---------------------------------------------------------------------------
extern "C" void kernel_launch(void* const* d_in, const int* in_sizes, int n_in,
                              void* d_out, int out_size, void* d_ws, size_t ws_size,
                              hipStream_t stream) {
    const float* x        = (const float*)d_in[0];
    const float* weight   = (const float*)d_in[1];
    const float* psi_vals = (const float*)d_in[2];
    const int*   psi_hi   = (const int*)d_in[3];
    const int*   psi_dw   = (const int*)d_in[4];
    float* out = (float*)d_out;

    // workspace: xr bf16 [721][1440][32] = 66,447,360 B, then
    // weff bf16 [721][20][32][32] = 29,532,160 B
    unsigned short* xr = (unsigned short*)d_ws;
    unsigned short* wf = (unsigned short*)((char*)d_ws + (size_t)NLAT_OUT * NLON_OUT * CH * 2);

    {
        dim3 grid(NLON_OUT / W_TILE, NLAT_OUT);   // 8 x 721
        resample_kernel<<<grid, 256, 0, stream>>>(x, xr);
    }
    {
        int nblk = (NLAT_OUT * NNZ + 15) / 16;    // 902
        weff_kernel<<<nblk, 256, 0, stream>>>(weight, psi_vals, wf);
    }
    {
        disco_kernel<<<8 * PER_XCD, 256, 0, stream>>>(xr, wf, psi_hi, psi_dw, out);
    }
}